// Round 11
// baseline (274.706 us; speedup 1.0000x reference)
//
#include <hip/hip_runtime.h>
#include <hip/hip_fp16.h>
#include <math.h>

#define N_NODES 12000
#define C 128
#define NEDGE 192000
#define BW 384  // u32 words per LDS dedup bitset (12288 bits >= 12000)

// acc_lo += (float)f16_lo(u); acc_hi += (float)f16_hi(u)  -- one VOP3P each
__device__ __forceinline__ void fmix2(float& lo, float& hi, unsigned u, float one) {
    asm("v_fma_mix_f32 %0, %2, %3, %0 op_sel:[0,0,0] op_sel_hi:[1,0,0]\n\t"
        "v_fma_mix_f32 %1, %2, %3, %1 op_sel:[1,0,0] op_sel_hi:[1,0,0]"
        : "+v"(lo), "+v"(hi)
        : "v"(u), "v"(one));
}

#define ACCM(p, u)                                            \
    fmix2(p##0, p##1, u.x, one); fmix2(p##2, p##3, u.y, one); \
    fmix2(p##4, p##5, u.z, one); fmix2(p##6, p##7, u.w, one)

#define RED2(x) x += __shfl_xor(x, 16); x += __shfl_xor(x, 32)

// ---- fused: x (fp32) -> f16 packed pairs  +  out-degree histogram ----
__global__ void prep(const float* __restrict__ x, unsigned* __restrict__ xbu,
                     const int* __restrict__ ei, int* __restrict__ deg) {
    int g = blockIdx.x * blockDim.x + threadIdx.x;
    if (g < N_NODES * C / 2) {
        unsigned pa = __half_as_ushort(__float2half(x[2 * g]));
        unsigned pb = __half_as_ushort(__float2half(x[2 * g + 1]));
        xbu[g] = pa | (pb << 16);
    }
    if (g < NEDGE) atomicAdd(&deg[ei[g]], 1);
}

// ---- exclusive scan of degrees -> CSR offsets (single 1024-thread block) ----
__global__ __launch_bounds__(1024) void scan_offsets(const int* __restrict__ deg,
                                                     int* __restrict__ off) {
    __shared__ int wsum[16];
    const int t = threadIdx.x;
    const int lane = t & 63, wv = t >> 6;
    const int PER = 12;  // 1024*12 = 12288 >= 12000
    const int lo = t * PER;
    int local[PER];
    int sum = 0;
#pragma unroll
    for (int k = 0; k < PER; ++k) {
        int i = lo + k;
        int d = (i < N_NODES) ? deg[i] : 0;
        local[k] = sum;
        sum += d;
    }
    int p = sum;
    for (int d = 1; d < 64; d <<= 1) {
        int u = __shfl_up(p, d);
        if (lane >= d) p += u;
    }
    if (lane == 63) wsum[wv] = p;
    __syncthreads();
    int wbase = 0;
    for (int k = 0; k < wv; ++k) wbase += wsum[k];
    const int tbase = wbase + p - sum;
#pragma unroll
    for (int k = 0; k < PER; ++k) {
        int i = lo + k;
        if (i < N_NODES) off[i] = tbase + local[k];
    }
    if (t == 0) off[N_NODES] = NEDGE;
}

// ---- fill CSR columns (order within row irrelevant; duplicates kept) ----
__global__ void fill_csr(const int* __restrict__ ei, const int* __restrict__ off,
                         int* __restrict__ cur, int* __restrict__ col) {
    int e = blockIdx.x * blockDim.x + threadIdx.x;
    if (e >= NEDGE) return;
    int s = ei[e];
    int t = ei[NEDGE + e];
    int pos = atomicAdd(&cur[s], 1);
    col[off[s] + pos] = t;
}

// ---- fused: agg1 (f16 CSR gather) + flattened 2-hop union + list gather ----
// (verbatim round-8 kernel: 71 us, verified)
__global__ __launch_bounds__(256) void twohop_fused(const int* __restrict__ off,
                                                    const int* __restrict__ col,
                                                    const unsigned* __restrict__ xb,
                                                    float* __restrict__ agg1,
                                                    float* __restrict__ agg2) {
    __shared__ unsigned acc[BW];          // 1.5 KB dedup bitset
    __shared__ int sjb[64];
    __shared__ int spos[64];
    __shared__ int stot;
    __shared__ int wtot[2];
    __shared__ unsigned short lst[4096];  // 8 KB; chunk cap = 128 words * 32 bits
    __shared__ float red[4][256];         // 4 KB
    const int i = blockIdx.x;
    const int tid = threadIdx.x;
    const int lane = tid & 63;
    const int wv = tid >> 6;
    const int grp = tid >> 4, l16 = tid & 15;
    const int rowbeg = off[i], rowend = off[i + 1];
    const uint4* xb4 = (const uint4*)xb;
    const float one = 1.0f;

    for (int w = tid; w < BW; w += 256) acc[w] = 0u;
    __syncthreads();  // acc ready for atomics

    // ---- 2-hop union, flattened per 64-neighbor chunk ----
    for (int base = rowbeg; base < rowend; base += 64) {
        int d = rowend - base;
        if (d > 64) d = 64;
        if (tid < 64) {
            int len = 0;
            if (tid < d) {
                int j = col[base + tid];
                int jb = off[j];
                len = off[j + 1] - jb;
                sjb[tid] = jb;
            }
            int p = len;
            for (int dd = 1; dd < 64; dd <<= 1) {
                int u = __shfl_up(p, dd);
                if (lane >= dd) p += u;
            }
            spos[tid] = p - len;  // exclusive
            if (tid == 63) stot = p;
        }
        __syncthreads();
        const int total = stot;
        for (int q = tid; q < total; q += 256) {
            int lo = 0, hi = d - 1;  // largest k with spos[k] <= q
            while (lo < hi) {
                int mid = (lo + hi + 1) >> 1;
                if (spos[mid] <= q) lo = mid; else hi = mid - 1;
            }
            int t = col[sjb[lo] + (q - spos[lo])];
            atomicOr(&acc[t >> 5], 1u << (t & 31));
        }
        __syncthreads();
    }
    if (tid == 0) acc[i >> 5] &= ~(1u << (i & 31));  // zero diagonal

    // ---- agg1: f16 counted gather over own row (multiplicity kept), 2x unrolled ----
    float b0 = 0, b1 = 0, b2 = 0, b3 = 0, b4 = 0, b5 = 0, b6 = 0, b7 = 0;
    {
        int idx = rowbeg + grp;
        for (; idx + 16 < rowend; idx += 32) {
            int k0 = col[idx], k1 = col[idx + 16];
            uint4 u0 = xb4[(unsigned)((k0 << 4) | l16)];
            uint4 u1 = xb4[(unsigned)((k1 << 4) | l16)];
            ACCM(b, u0);
            ACCM(b, u1);
        }
        if (idx < rowend) {
            int k0 = col[idx];
            uint4 u0 = xb4[(unsigned)((k0 << 4) | l16)];
            ACCM(b, u0);
        }
    }

    // ---- agg2: per-chunk enumerate (prefix-scan) + counted gather, 4x unrolled ----
    float a0 = 0, a1 = 0, a2 = 0, a3 = 0, a4 = 0, a5 = 0, a6 = 0, a7 = 0;
    for (int chunk = 0; chunk < 3; ++chunk) {
        __syncthreads();  // chunk 0: diag clear visible; others: lst consumed
        unsigned v = 0;
        int n = 0, p = 0;
        if (tid < 128) {
            v = acc[chunk * 128 + tid];
            n = __popc(v);
            p = n;
            for (int dd = 1; dd < 64; dd <<= 1) {
                int u = __shfl_up(p, dd);
                if (lane >= dd) p += u;
            }
            if (lane == 63) wtot[wv] = p;
        }
        __syncthreads();
        if (tid < 128) {
            int o = ((wv == 1) ? wtot[0] : 0) + p - n;
            int wbase = (chunk * 128 + tid) << 5;
            while (v) {
                int b = __ffs(v) - 1;
                v &= v - 1;
                lst[o++] = (unsigned short)(wbase + b);
            }
        }
        __syncthreads();
        const int total = wtot[0] + wtot[1];
        int q = grp;
        for (; q + 48 < total; q += 64) {
            int k0 = lst[q], k1 = lst[q + 16], k2 = lst[q + 32], k3 = lst[q + 48];
            uint4 u0 = xb4[(unsigned)((k0 << 4) | l16)];
            uint4 u1 = xb4[(unsigned)((k1 << 4) | l16)];
            uint4 u2 = xb4[(unsigned)((k2 << 4) | l16)];
            uint4 u3 = xb4[(unsigned)((k3 << 4) | l16)];
            ACCM(a, u0);
            ACCM(a, u1);
            ACCM(a, u2);
            ACCM(a, u3);
        }
        for (; q + 16 < total; q += 32) {
            int k0 = lst[q], k1 = lst[q + 16];
            uint4 u0 = xb4[(unsigned)((k0 << 4) | l16)];
            uint4 u1 = xb4[(unsigned)((k1 << 4) | l16)];
            ACCM(a, u0);
            ACCM(a, u1);
        }
        if (q < total) {
            int k0 = lst[q];
            uint4 u0 = xb4[(unsigned)((k0 << 4) | l16)];
            ACCM(a, u0);
        }
    }

    // ---- cross-group reduction: shuffle within wave, then 4-wave LDS combine ----
    RED2(a0); RED2(a1); RED2(a2); RED2(a3); RED2(a4); RED2(a5); RED2(a6); RED2(a7);
    RED2(b0); RED2(b1); RED2(b2); RED2(b3); RED2(b4); RED2(b5); RED2(b6); RED2(b7);
    __syncthreads();
    if (lane < 16) {
        red[wv][l16 * 8 + 0] = a0; red[wv][l16 * 8 + 1] = a1;
        red[wv][l16 * 8 + 2] = a2; red[wv][l16 * 8 + 3] = a3;
        red[wv][l16 * 8 + 4] = a4; red[wv][l16 * 8 + 5] = a5;
        red[wv][l16 * 8 + 6] = a6; red[wv][l16 * 8 + 7] = a7;
        red[wv][128 + l16 * 8 + 0] = b0; red[wv][128 + l16 * 8 + 1] = b1;
        red[wv][128 + l16 * 8 + 2] = b2; red[wv][128 + l16 * 8 + 3] = b3;
        red[wv][128 + l16 * 8 + 4] = b4; red[wv][128 + l16 * 8 + 5] = b5;
        red[wv][128 + l16 * 8 + 6] = b6; red[wv][128 + l16 * 8 + 7] = b7;
    }
    __syncthreads();
    float s = red[0][tid] + red[1][tid] + red[2][tid] + red[3][tid];
    if (tid < 128) agg2[(size_t)i * C + tid] = s;
    else           agg1[(size_t)i * C + (tid - 128)] = s;
}

// ---- fuse/transpose weights (runs once per call; weights-only, ~5 us) ----
// W1t[c][j] = W1[j][c]; Wf1t[c][j] = sum_k W1[j][k]*Wg[k][c]  (gate fusion)
// bfused[c] = sum_k b1[k]*Wg[k][c] + sum_k b2[k]*Wg[128+k][c] + bg[c]
__global__ __launch_bounds__(128) void fuse_weights(const float* __restrict__ W1,
                                                    const float* __restrict__ W2,
                                                    const float* __restrict__ Wg,
                                                    const float* __restrict__ b1,
                                                    const float* __restrict__ b2,
                                                    const float* __restrict__ bg,
                                                    float* __restrict__ W1t,
                                                    float* __restrict__ W2t,
                                                    float* __restrict__ Wf1t,
                                                    float* __restrict__ Wf2t,
                                                    float* __restrict__ bfused) {
    __shared__ __align__(16) float wg1[C];
    __shared__ __align__(16) float wg2[C];
    __shared__ float sb[C];
    const int c = blockIdx.x, j = threadIdx.x;
    float g1 = Wg[(size_t)j * C + c];
    float g2 = Wg[(size_t)(C + j) * C + c];
    wg1[j] = g1;
    wg2[j] = g2;
    sb[j] = b1[j] * g1 + b2[j] * g2;
    __syncthreads();
    float s1 = 0.f, s2 = 0.f;
    for (int k = 0; k < C; k += 4) {
        float4 a = *(const float4*)&W1[(size_t)j * C + k];
        float4 b = *(const float4*)&W2[(size_t)j * C + k];
        float4 u = *(const float4*)&wg1[k];
        float4 v = *(const float4*)&wg2[k];
        s1 += a.x * u.x + a.y * u.y + a.z * u.z + a.w * u.w;
        s2 += b.x * v.x + b.y * v.y + b.z * v.z + b.w * v.w;
    }
    Wf1t[(size_t)c * C + j] = s1;
    Wf2t[(size_t)c * C + j] = s2;
    W1t[(size_t)c * C + j] = W1[(size_t)j * C + c];
    W2t[(size_t)c * C + j] = W2[(size_t)j * C + c];
    if (j == 0) {
        float s = bg[c];
        for (int k = 0; k < C; ++k) s += sb[k];
        bfused[c] = s;
    }
}

// ---- epilogue, LDS-free: 4 rows/block, 3000 blocks, 128 threads ----
// agg reads are wave-uniform (scalar loads); weight reads coalesced float4.
__global__ __launch_bounds__(128) void epilogue(const float* __restrict__ agg1,
                                                const float* __restrict__ agg2,
                                                const float* __restrict__ W1t,
                                                const float* __restrict__ W2t,
                                                const float* __restrict__ Wf1t,
                                                const float* __restrict__ Wf2t,
                                                const float* __restrict__ b1,
                                                const float* __restrict__ b2,
                                                const float* __restrict__ bfused,
                                                float* __restrict__ out) {
    const int c = threadIdx.x;
    const int r0 = blockIdx.x * 4;
    const float4* w1 = (const float4*)(W1t + (size_t)c * C);
    const float4* w2 = (const float4*)(W2t + (size_t)c * C);
    const float4* f1 = (const float4*)(Wf1t + (size_t)c * C);
    const float4* f2 = (const float4*)(Wf2t + (size_t)c * C);

    float z1v[4] = {0.f, 0.f, 0.f, 0.f};
    float z2v[4] = {0.f, 0.f, 0.f, 0.f};
    float gv[4]  = {0.f, 0.f, 0.f, 0.f};
    for (int k4 = 0; k4 < C / 4; ++k4) {
        float4 a = w1[k4], b = w2[k4], p = f1[k4], q = f2[k4];
#pragma unroll
        for (int r = 0; r < 4; ++r) {
            float4 u = *(const float4*)&agg1[(size_t)(r0 + r) * C + k4 * 4];  // uniform -> s_load
            float4 v = *(const float4*)&agg2[(size_t)(r0 + r) * C + k4 * 4];
            z1v[r] += u.x * a.x + u.y * a.y + u.z * a.z + u.w * a.w;
            z2v[r] += v.x * b.x + v.y * b.y + v.z * b.z + v.w * b.w;
            gv[r]  += u.x * p.x + u.y * p.y + u.z * p.z + u.w * p.w
                    + v.x * q.x + v.y * q.y + v.z * q.z + v.w * q.w;
        }
    }
    const float b1v = b1[c], b2v = b2[c], bfv = bfused[c];
#pragma unroll
    for (int r = 0; r < 4; ++r) {
        float z1 = z1v[r] + b1v;
        float z2 = z2v[r] + b2v;
        float g = 1.f / (1.f + expf(-(gv[r] + bfv)));
        out[(size_t)(r0 + r) * C + c] = g * z1 + (1.f - g) * z2;
    }
}

extern "C" void kernel_launch(void* const* d_in, const int* in_sizes, int n_in,
                              void* d_out, int out_size, void* d_ws, size_t ws_size,
                              hipStream_t stream) {
    const float* x  = (const float*)d_in[0];
    const int*   ei = (const int*)d_in[1];
    const float* W1 = (const float*)d_in[2];
    const float* b1 = (const float*)d_in[3];
    const float* W2 = (const float*)d_in[4];
    const float* b2 = (const float*)d_in[5];
    const float* Wg = (const float*)d_in[6];
    const float* bg = (const float*)d_in[7];
    float* out = (float*)d_out;

    char* ws = (char*)d_ws;
    size_t o = 0;
    auto alloc = [&](size_t bytes) { char* p = ws + o; o = (o + bytes + 255) & ~(size_t)255; return p; };
    int* col      = (int*)alloc((size_t)NEDGE * 4);
    int* deg      = (int*)alloc((size_t)N_NODES * 2 * 4);   // deg + cur contiguous
    int* cur      = deg + N_NODES;
    int* off      = (int*)alloc((size_t)(N_NODES + 1) * 4);
    unsigned* xb  = (unsigned*)alloc((size_t)N_NODES * C * 2);  // f16 x
    float* agg1   = (float*)alloc((size_t)N_NODES * C * 4);
    float* agg2   = (float*)alloc((size_t)N_NODES * C * 4);
    float* W1t    = (float*)alloc((size_t)C * C * 4);
    float* W2t    = (float*)alloc((size_t)C * C * 4);
    float* Wf1t   = (float*)alloc((size_t)C * C * 4);
    float* Wf2t   = (float*)alloc((size_t)C * C * 4);
    float* bfused = (float*)alloc((size_t)C * 4);
    // total ~16.6 MB (round-8 footprint + 0.26 MB; proven safe)

    hipMemsetAsync(deg, 0, (size_t)N_NODES * 2 * 4, stream);

    prep<<<(N_NODES * C / 2 + 255) / 256, 256, 0, stream>>>(x, xb, ei, deg);
    fuse_weights<<<C, 128, 0, stream>>>(W1, W2, Wg, b1, b2, bg, W1t, W2t, Wf1t, Wf2t, bfused);
    scan_offsets<<<1, 1024, 0, stream>>>(deg, off);
    fill_csr<<<(NEDGE + 255) / 256, 256, 0, stream>>>(ei, off, cur, col);
    twohop_fused<<<N_NODES, 256, 0, stream>>>(off, col, xb, agg1, agg2);
    epilogue<<<N_NODES / 4, 128, 0, stream>>>(agg1, agg2, W1t, W2t, Wf1t, Wf2t, b1, b2, bfused, out);
}

// Round 12
// 165.933 us; speedup vs baseline: 1.6555x; 1.6555x over previous
//
#include <hip/hip_runtime.h>
#include <hip/hip_fp16.h>
#include <math.h>

#define N_NODES 12000
#define C 128
#define NEDGE 192000
#define BW 384  // u32 words per LDS dedup bitset (12288 bits >= 12000)

// acc_lo += (float)f16_lo(u); acc_hi += (float)f16_hi(u)  -- one VOP3P each
__device__ __forceinline__ void fmix2(float& lo, float& hi, unsigned u, float one) {
    asm("v_fma_mix_f32 %0, %2, %3, %0 op_sel:[0,0,0] op_sel_hi:[1,0,0]\n\t"
        "v_fma_mix_f32 %1, %2, %3, %1 op_sel:[1,0,0] op_sel_hi:[1,0,0]"
        : "+v"(lo), "+v"(hi)
        : "v"(u), "v"(one));
}

#define ACCM(p, u)                                            \
    fmix2(p##0, p##1, u.x, one); fmix2(p##2, p##3, u.y, one); \
    fmix2(p##4, p##5, u.z, one); fmix2(p##6, p##7, u.w, one)

#define RED2(x) x += __shfl_xor(x, 16); x += __shfl_xor(x, 32)

// ---- fused: x (fp32) -> f16 packed pairs  +  out-degree histogram ----
__global__ void prep(const float* __restrict__ x, unsigned* __restrict__ xbu,
                     const int* __restrict__ ei, int* __restrict__ deg) {
    int g = blockIdx.x * blockDim.x + threadIdx.x;
    if (g < N_NODES * C / 2) {
        unsigned pa = __half_as_ushort(__float2half(x[2 * g]));
        unsigned pb = __half_as_ushort(__float2half(x[2 * g + 1]));
        xbu[g] = pa | (pb << 16);
    }
    if (g < NEDGE) atomicAdd(&deg[ei[g]], 1);
}

// ---- exclusive scan of degrees -> CSR offsets (single 1024-thread block) ----
__global__ __launch_bounds__(1024) void scan_offsets(const int* __restrict__ deg,
                                                     int* __restrict__ off) {
    __shared__ int wsum[16];
    const int t = threadIdx.x;
    const int lane = t & 63, wv = t >> 6;
    const int PER = 12;  // 1024*12 = 12288 >= 12000
    const int lo = t * PER;
    int local[PER];
    int sum = 0;
#pragma unroll
    for (int k = 0; k < PER; ++k) {
        int i = lo + k;
        int d = (i < N_NODES) ? deg[i] : 0;
        local[k] = sum;
        sum += d;
    }
    int p = sum;
    for (int d = 1; d < 64; d <<= 1) {
        int u = __shfl_up(p, d);
        if (lane >= d) p += u;
    }
    if (lane == 63) wsum[wv] = p;
    __syncthreads();
    int wbase = 0;
    for (int k = 0; k < wv; ++k) wbase += wsum[k];
    const int tbase = wbase + p - sum;
#pragma unroll
    for (int k = 0; k < PER; ++k) {
        int i = lo + k;
        if (i < N_NODES) off[i] = tbase + local[k];
    }
    if (t == 0) off[N_NODES] = NEDGE;
}

// ---- fill CSR columns (order within row irrelevant; duplicates kept) ----
__global__ void fill_csr(const int* __restrict__ ei, const int* __restrict__ off,
                         int* __restrict__ cur, int* __restrict__ col) {
    int e = blockIdx.x * blockDim.x + threadIdx.x;
    if (e >= NEDGE) return;
    int s = ei[e];
    int t = ei[NEDGE + e];
    int pos = atomicAdd(&cur[s], 1);
    col[off[s] + pos] = t;
}

// ---- fused: agg1 (f16 CSR gather) + flattened 2-hop union + list gather ----
// (verbatim round-8 kernel: 71 us, verified)
__global__ __launch_bounds__(256) void twohop_fused(const int* __restrict__ off,
                                                    const int* __restrict__ col,
                                                    const unsigned* __restrict__ xb,
                                                    float* __restrict__ agg1,
                                                    float* __restrict__ agg2) {
    __shared__ unsigned acc[BW];          // 1.5 KB dedup bitset
    __shared__ int sjb[64];
    __shared__ int spos[64];
    __shared__ int stot;
    __shared__ int wtot[2];
    __shared__ unsigned short lst[4096];  // 8 KB; chunk cap = 128 words * 32 bits
    __shared__ float red[4][256];         // 4 KB
    const int i = blockIdx.x;
    const int tid = threadIdx.x;
    const int lane = tid & 63;
    const int wv = tid >> 6;
    const int grp = tid >> 4, l16 = tid & 15;
    const int rowbeg = off[i], rowend = off[i + 1];
    const uint4* xb4 = (const uint4*)xb;
    const float one = 1.0f;

    for (int w = tid; w < BW; w += 256) acc[w] = 0u;
    __syncthreads();  // acc ready for atomics

    // ---- 2-hop union, flattened per 64-neighbor chunk ----
    for (int base = rowbeg; base < rowend; base += 64) {
        int d = rowend - base;
        if (d > 64) d = 64;
        if (tid < 64) {
            int len = 0;
            if (tid < d) {
                int j = col[base + tid];
                int jb = off[j];
                len = off[j + 1] - jb;
                sjb[tid] = jb;
            }
            int p = len;
            for (int dd = 1; dd < 64; dd <<= 1) {
                int u = __shfl_up(p, dd);
                if (lane >= dd) p += u;
            }
            spos[tid] = p - len;  // exclusive
            if (tid == 63) stot = p;
        }
        __syncthreads();
        const int total = stot;
        for (int q = tid; q < total; q += 256) {
            int lo = 0, hi = d - 1;  // largest k with spos[k] <= q
            while (lo < hi) {
                int mid = (lo + hi + 1) >> 1;
                if (spos[mid] <= q) lo = mid; else hi = mid - 1;
            }
            int t = col[sjb[lo] + (q - spos[lo])];
            atomicOr(&acc[t >> 5], 1u << (t & 31));
        }
        __syncthreads();
    }
    if (tid == 0) acc[i >> 5] &= ~(1u << (i & 31));  // zero diagonal

    // ---- agg1: f16 counted gather over own row (multiplicity kept), 2x unrolled ----
    float b0 = 0, b1 = 0, b2 = 0, b3 = 0, b4 = 0, b5 = 0, b6 = 0, b7 = 0;
    {
        int idx = rowbeg + grp;
        for (; idx + 16 < rowend; idx += 32) {
            int k0 = col[idx], k1 = col[idx + 16];
            uint4 u0 = xb4[(unsigned)((k0 << 4) | l16)];
            uint4 u1 = xb4[(unsigned)((k1 << 4) | l16)];
            ACCM(b, u0);
            ACCM(b, u1);
        }
        if (idx < rowend) {
            int k0 = col[idx];
            uint4 u0 = xb4[(unsigned)((k0 << 4) | l16)];
            ACCM(b, u0);
        }
    }

    // ---- agg2: per-chunk enumerate (prefix-scan) + counted gather, 4x unrolled ----
    float a0 = 0, a1 = 0, a2 = 0, a3 = 0, a4 = 0, a5 = 0, a6 = 0, a7 = 0;
    for (int chunk = 0; chunk < 3; ++chunk) {
        __syncthreads();  // chunk 0: diag clear visible; others: lst consumed
        unsigned v = 0;
        int n = 0, p = 0;
        if (tid < 128) {
            v = acc[chunk * 128 + tid];
            n = __popc(v);
            p = n;
            for (int dd = 1; dd < 64; dd <<= 1) {
                int u = __shfl_up(p, dd);
                if (lane >= dd) p += u;
            }
            if (lane == 63) wtot[wv] = p;
        }
        __syncthreads();
        if (tid < 128) {
            int o = ((wv == 1) ? wtot[0] : 0) + p - n;
            int wbase = (chunk * 128 + tid) << 5;
            while (v) {
                int b = __ffs(v) - 1;
                v &= v - 1;
                lst[o++] = (unsigned short)(wbase + b);
            }
        }
        __syncthreads();
        const int total = wtot[0] + wtot[1];
        int q = grp;
        for (; q + 48 < total; q += 64) {
            int k0 = lst[q], k1 = lst[q + 16], k2 = lst[q + 32], k3 = lst[q + 48];
            uint4 u0 = xb4[(unsigned)((k0 << 4) | l16)];
            uint4 u1 = xb4[(unsigned)((k1 << 4) | l16)];
            uint4 u2 = xb4[(unsigned)((k2 << 4) | l16)];
            uint4 u3 = xb4[(unsigned)((k3 << 4) | l16)];
            ACCM(a, u0);
            ACCM(a, u1);
            ACCM(a, u2);
            ACCM(a, u3);
        }
        for (; q + 16 < total; q += 32) {
            int k0 = lst[q], k1 = lst[q + 16];
            uint4 u0 = xb4[(unsigned)((k0 << 4) | l16)];
            uint4 u1 = xb4[(unsigned)((k1 << 4) | l16)];
            ACCM(a, u0);
            ACCM(a, u1);
        }
        if (q < total) {
            int k0 = lst[q];
            uint4 u0 = xb4[(unsigned)((k0 << 4) | l16)];
            ACCM(a, u0);
        }
    }

    // ---- cross-group reduction: shuffle within wave, then 4-wave LDS combine ----
    RED2(a0); RED2(a1); RED2(a2); RED2(a3); RED2(a4); RED2(a5); RED2(a6); RED2(a7);
    RED2(b0); RED2(b1); RED2(b2); RED2(b3); RED2(b4); RED2(b5); RED2(b6); RED2(b7);
    __syncthreads();
    if (lane < 16) {
        red[wv][l16 * 8 + 0] = a0; red[wv][l16 * 8 + 1] = a1;
        red[wv][l16 * 8 + 2] = a2; red[wv][l16 * 8 + 3] = a3;
        red[wv][l16 * 8 + 4] = a4; red[wv][l16 * 8 + 5] = a5;
        red[wv][l16 * 8 + 6] = a6; red[wv][l16 * 8 + 7] = a7;
        red[wv][128 + l16 * 8 + 0] = b0; red[wv][128 + l16 * 8 + 1] = b1;
        red[wv][128 + l16 * 8 + 2] = b2; red[wv][128 + l16 * 8 + 3] = b3;
        red[wv][128 + l16 * 8 + 4] = b4; red[wv][128 + l16 * 8 + 5] = b5;
        red[wv][128 + l16 * 8 + 6] = b6; red[wv][128 + l16 * 8 + 7] = b7;
    }
    __syncthreads();
    float s = red[0][tid] + red[1][tid] + red[2][tid] + red[3][tid];
    if (tid < 128) agg2[(size_t)i * C + tid] = s;
    else           agg1[(size_t)i * C + (tid - 128)] = s;
}

// ---- fuse weights for gate: Wf1[j][c] = sum_k W1[j][k]*Wg[k][c] ([k][c] layout!),
//      bfused[c] = b1@Wg_top + b2@Wg_bot + bg ----
__global__ __launch_bounds__(128) void fuse_weights(const float* __restrict__ W1,
                                                    const float* __restrict__ W2,
                                                    const float* __restrict__ Wg,
                                                    const float* __restrict__ b1,
                                                    const float* __restrict__ b2,
                                                    const float* __restrict__ bg,
                                                    float* __restrict__ Wf1,
                                                    float* __restrict__ Wf2,
                                                    float* __restrict__ bfused) {
    __shared__ __align__(16) float wg1[C];
    __shared__ __align__(16) float wg2[C];
    __shared__ float sb[C];
    const int c = blockIdx.x, j = threadIdx.x;
    float g1 = Wg[(size_t)j * C + c];
    float g2 = Wg[(size_t)(C + j) * C + c];
    wg1[j] = g1;
    wg2[j] = g2;
    sb[j] = b1[j] * g1 + b2[j] * g2;
    __syncthreads();
    float s1 = 0.f, s2 = 0.f;
    for (int k = 0; k < C; k += 4) {
        float4 a = *(const float4*)&W1[(size_t)j * C + k];
        float4 b = *(const float4*)&W2[(size_t)j * C + k];
        float4 u = *(const float4*)&wg1[k];
        float4 v = *(const float4*)&wg2[k];
        s1 += a.x * u.x + a.y * u.y + a.z * u.z + a.w * u.w;
        s2 += b.x * v.x + b.y * v.y + b.z * v.z + b.w * v.w;
    }
    Wf1[(size_t)j * C + c] = s1;  // [k][c] layout, same as W1
    Wf2[(size_t)j * C + c] = s2;
    if (j == 0) {
        float s = bg[c];
        for (int k = 0; k < C; ++k) s += sb[k];
        bfused[c] = s;
    }
}

// ---- single-pass epilogue: 16 rows/block, 2 cols/thread, fused gate ----
// z1,z2,gate logits in ONE k-loop; coalesced float2 weight reads; 1 barrier.
__global__ __launch_bounds__(256) void epilogue(const float* __restrict__ agg1,
                                                const float* __restrict__ agg2,
                                                const float* __restrict__ W1,
                                                const float* __restrict__ W2,
                                                const float* __restrict__ Wf1,
                                                const float* __restrict__ Wf2,
                                                const float* __restrict__ b1,
                                                const float* __restrict__ b2,
                                                const float* __restrict__ bfused,
                                                float* __restrict__ out) {
    __shared__ float sA[16][C];  // 8 KB
    __shared__ float sB[16][C];  // 8 KB
    const int r0 = blockIdx.x * 16;
    const int tid = threadIdx.x;
    const int c0 = (tid & 63) * 2;   // columns c0, c0+1
    const int rg = (tid >> 6) * 4;   // 4 rows per thread

    for (int idx = tid; idx < 16 * C / 4; idx += 256) {
        int r = idx >> 5, k4 = idx & 31;
        ((float4*)sA[r])[k4] = ((const float4*)&agg1[(size_t)(r0 + r) * C])[k4];
        ((float4*)sB[r])[k4] = ((const float4*)&agg2[(size_t)(r0 + r) * C])[k4];
    }
    __syncthreads();

    float z1v[4][2] = {}, z2v[4][2] = {}, gv[4][2] = {};
    for (int k = 0; k < C; k += 4) {
        float2 w1q[4], w2q[4], f1q[4], f2q[4];
#pragma unroll
        for (int kk = 0; kk < 4; ++kk) {
            w1q[kk] = *(const float2*)&W1[(size_t)(k + kk) * C + c0];
            w2q[kk] = *(const float2*)&W2[(size_t)(k + kk) * C + c0];
            f1q[kk] = *(const float2*)&Wf1[(size_t)(k + kk) * C + c0];
            f2q[kk] = *(const float2*)&Wf2[(size_t)(k + kk) * C + c0];
        }
#pragma unroll
        for (int r = 0; r < 4; ++r) {
            float4 a4 = *(const float4*)&sA[rg + r][k];
            float4 b4 = *(const float4*)&sB[rg + r][k];
            float av[4] = {a4.x, a4.y, a4.z, a4.w};
            float bv[4] = {b4.x, b4.y, b4.z, b4.w};
#pragma unroll
            for (int kk = 0; kk < 4; ++kk) {
                z1v[r][0] += av[kk] * w1q[kk].x;  z1v[r][1] += av[kk] * w1q[kk].y;
                z2v[r][0] += bv[kk] * w2q[kk].x;  z2v[r][1] += bv[kk] * w2q[kk].y;
                gv[r][0]  += av[kk] * f1q[kk].x + bv[kk] * f2q[kk].x;
                gv[r][1]  += av[kk] * f1q[kk].y + bv[kk] * f2q[kk].y;
            }
        }
    }
    const float2 b1v = *(const float2*)&b1[c0];
    const float2 b2v = *(const float2*)&b2[c0];
    const float2 bfv = *(const float2*)&bfused[c0];
#pragma unroll
    for (int r = 0; r < 4; ++r) {
        float g0 = 1.f / (1.f + expf(-(gv[r][0] + bfv.x)));
        float g1 = 1.f / (1.f + expf(-(gv[r][1] + bfv.y)));
        float2 res;
        res.x = g0 * (z1v[r][0] + b1v.x) + (1.f - g0) * (z2v[r][0] + b2v.x);
        res.y = g1 * (z1v[r][1] + b1v.y) + (1.f - g1) * (z2v[r][1] + b2v.y);
        *(float2*)&out[(size_t)(r0 + rg + r) * C + c0] = res;
    }
}

extern "C" void kernel_launch(void* const* d_in, const int* in_sizes, int n_in,
                              void* d_out, int out_size, void* d_ws, size_t ws_size,
                              hipStream_t stream) {
    const float* x  = (const float*)d_in[0];
    const int*   ei = (const int*)d_in[1];
    const float* W1 = (const float*)d_in[2];
    const float* b1 = (const float*)d_in[3];
    const float* W2 = (const float*)d_in[4];
    const float* b2 = (const float*)d_in[5];
    const float* Wg = (const float*)d_in[6];
    const float* bg = (const float*)d_in[7];
    float* out = (float*)d_out;

    char* ws = (char*)d_ws;
    size_t o = 0;
    auto alloc = [&](size_t bytes) { char* p = ws + o; o = (o + bytes + 255) & ~(size_t)255; return p; };
    int* col      = (int*)alloc((size_t)NEDGE * 4);
    int* deg      = (int*)alloc((size_t)N_NODES * 2 * 4);   // deg + cur contiguous
    int* cur      = deg + N_NODES;
    int* off      = (int*)alloc((size_t)(N_NODES + 1) * 4);
    unsigned* xb  = (unsigned*)alloc((size_t)N_NODES * C * 2);  // f16 x
    float* agg1   = (float*)alloc((size_t)N_NODES * C * 4);
    float* agg2   = (float*)alloc((size_t)N_NODES * C * 4);
    float* Wf1    = (float*)alloc((size_t)C * C * 4);
    float* Wf2    = (float*)alloc((size_t)C * C * 4);
    float* bfused = (float*)alloc((size_t)C * 4);
    // total ~16.5 MB (round-8 footprint + 0.13 MB; proven safe)

    hipMemsetAsync(deg, 0, (size_t)N_NODES * 2 * 4, stream);

    prep<<<(N_NODES * C / 2 + 255) / 256, 256, 0, stream>>>(x, xb, ei, deg);
    fuse_weights<<<C, 128, 0, stream>>>(W1, W2, Wg, b1, b2, bg, Wf1, Wf2, bfused);
    scan_offsets<<<1, 1024, 0, stream>>>(deg, off);
    fill_csr<<<(NEDGE + 255) / 256, 256, 0, stream>>>(ei, off, cur, col);
    twohop_fused<<<N_NODES, 256, 0, stream>>>(off, col, xb, agg1, agg2);
    epilogue<<<N_NODES / 16, 256, 0, stream>>>(agg1, agg2, W1, W2, Wf1, Wf2, b1, b2, bfused, out);
}